// Round 8
// baseline (171.690 us; speedup 1.0000x reference)
//
#include <hip/hip_runtime.h>
#include <hip/hip_bf16.h>

typedef unsigned short u16;
typedef unsigned int u32;
typedef __attribute__((ext_vector_type(4))) float f32x4;
typedef __attribute__((ext_vector_type(16))) float f32x16;
typedef __attribute__((ext_vector_type(8))) short bf16x8;

__device__ inline u16 f2bf(float f) {
    union { float f; u32 u; } v; v.f = f;
    u32 r = v.u + 0x7fff + ((v.u >> 16) & 1);
    return (u16)(r >> 16);
}

__device__ inline f32x4 mfma16(bf16x8 a, bf16x8 b, f32x4 c) {
    return __builtin_amdgcn_mfma_f32_16x16x32_bf16(a, b, c, 0, 0, 0);
}
__device__ inline f32x16 mfma32(bf16x8 a, bf16x8 b, f32x16 c) {
    return __builtin_amdgcn_mfma_f32_32x32x16_bf16(a, b, c, 0, 0, 0);
}
__device__ inline u32 cvtpk(float lo, float hi) {
    u32 r;
    asm("v_cvt_pk_bf16_f32 %0, %1, %2" : "=v"(r) : "v"(lo), "v"(hi));
    return r;
}
__device__ inline float exp2v(float x) {
    float r;
    asm("v_exp_f32 %0, %1" : "=v"(r) : "v"(x));
    return r;
}

__device__ inline void gload_lds16(const void* g, const void* l) {
    __builtin_amdgcn_global_load_lds(
        (const __attribute__((address_space(1))) void*)g,
        (__attribute__((address_space(3))) void*)l, 16, 0, 0);
}

// log2(e) * head_dim^-0.5 — folded into q in the QKV epilogue (base-2 softmax)
#define QSCALE 0.18033688f

// ---------------- fp32 -> bf16 conversion, 8 elems/thread ----------------
__global__ void cvt_kernel(const float* __restrict__ in, u16* __restrict__ out, int n8) {
    int i = blockIdx.x * 256 + threadIdx.x;
    if (i >= n8) return;
    const float4* p = (const float4*)in;
    float4 a = p[2 * i], b = p[2 * i + 1];
    bf16x8 v;
    v[0] = (short)f2bf(a.x); v[1] = (short)f2bf(a.y);
    v[2] = (short)f2bf(a.z); v[3] = (short)f2bf(a.w);
    v[4] = (short)f2bf(b.x); v[5] = (short)f2bf(b.y);
    v[6] = (short)f2bf(b.z); v[7] = (short)f2bf(b.w);
    ((bf16x8*)out)[i] = v;
}

// ================= QKV GEMM: 256x256 tile, BK=32, 8 waves ================
// C[8192,2304] = X[8192,768] * Wqkv[2304,768]^T. K=768 -> 24 K-tiles.
// 3-deep counted-vmcnt LDS pipeline (T3/T4), XOR-swizzled LDS (T2),
// setprio (T5), XCD swizzle (T1). SINGLE fragment set (no reg ping-pong —
// R7's 2-deep reg buffer forced a 128-VGPR spill; the 3 LDS buffers already
// carry the pipeline depth).
// Epilogue: Q row-major [bh][n][64]*QSCALE; K,V fragment-order:
//   Kf: (n,d) -> (bh<<16) + (n>>5)*2048 + (d>>3)*256 + (n&31)*8 + (d&7)
//   Vf: (n,d) -> (bh<<16) + (n>>5)*2048 + ((d>>5)*2+((n&31)>>4))*512
//               + (((n>>3)&1)*32 + (d&31))*8 + (n&7)
__global__ __launch_bounds__(512, 1) void gemm_qkv(
    const u16* __restrict__ A, const u16* __restrict__ B,
    u16* __restrict__ qw, u16* __restrict__ kw, u16* __restrict__ vw,
    const float* __restrict__ qb, const float* __restrict__ vb)
{
    // 96 KB: 3 K-tile buffers x (A: 2x4096 u16 halves | B: 2x4096 u16 halves)
    __shared__ __align__(16) u16 smem[49152];
    const int K = 768;
    const int NT = 24;                          // K / 32
    const int tid = threadIdx.x;
    const int lane = tid & 63, wv = tid >> 6;
    const int wm = wv >> 2, wn = wv & 3;       // 2M x 4N wave grid
    // bijective XCD swizzle, grid 288 (%8==0)
    const int wg = (blockIdx.x & 7) * 36 + (blockIdx.x >> 3);
    const int bm = wg / 9, bn = wg % 9;
    const int row0 = bm << 8, col0 = bn << 8;

    // ---- staging geometry: chunk c = tid of each 8KB half (128 rows x 64B)
    const int srow = tid >> 2;                         // 0..127
    const int sch = (tid & 3) ^ ((srow >> 1) & 3);     // swizzled data chunk
    const u16* gA = A + (size_t)(row0 + srow) * K + sch * 8;
    const u16* gB = B + (size_t)(col0 + srow) * K + sch * 8;
    const int ldst = wv * 512;                         // u16, wave-uniform

    auto stageTile = [&](int bufi, int t) {
        u16* base = &smem[bufi * 16384];
        const int k0 = t << 5;
        gload_lds16(gA + k0,                     base + ldst);
        gload_lds16(gA + (size_t)128 * K + k0,   base + 4096 + ldst);
        gload_lds16(gB + k0,                     base + 8192 + ldst);
        gload_lds16(gB + (size_t)128 * K + k0,   base + 12288 + ldst);
    };

    // ---- fragment reads (swizzled) ----
    const int arl = lane & 15, ahi = lane >> 4;
    auto loadFrags = [&](int bufi, bf16x8 (&fa)[8], bf16x8 (&fb)[4]) {
        const u16* bA = &smem[bufi * 16384 + wm * 4096];
        const u16* bB = &smem[bufi * 16384 + 8192 + (wn >> 1) * 4096];
#pragma unroll
        for (int fi = 0; fi < 8; ++fi) {
            const int rl = fi * 16 + arl;
            const int chc = ahi ^ ((rl >> 1) & 3);
            fa[fi] = *(const bf16x8*)(bA + rl * 32 + chc * 8);
        }
#pragma unroll
        for (int fj = 0; fj < 4; ++fj) {
            const int cl = ((wn & 1) << 6) + fj * 16 + arl;
            const int chc = ahi ^ ((cl >> 1) & 3);
            fb[fj] = *(const bf16x8*)(bB + cl * 32 + chc * 8);
        }
    };

    f32x4 acc[8][4];
#pragma unroll
    for (int i = 0; i < 8; ++i)
#pragma unroll
        for (int j = 0; j < 4; ++j) acc[i][j] = (f32x4){0.f, 0.f, 0.f, 0.f};

    auto mfmaTile = [&](bf16x8 (&fa)[8], bf16x8 (&fb)[4]) {
#pragma unroll
        for (int fi = 0; fi < 8; ++fi) {
            __builtin_amdgcn_s_setprio(1);
#pragma unroll
            for (int fj = 0; fj < 4; ++fj)
                acc[fi][fj] = mfma16(fa[fi], fb[fj], acc[fi][fj]);
            __builtin_amdgcn_s_setprio(0);
        }
    };

    bf16x8 fa[8], fb[4];

    // ---- prologue: stage tiles 0,1,2 (12 loads in flight) ----
    stageTile(0, 0); stageTile(1, 1); stageTile(2, 2);

    // ---- main loop: tiles 0..21; loads always 8-deep across barriers ----
#pragma unroll 1
    for (int t = 0; t < NT - 2; ++t) {
        asm volatile("s_waitcnt vmcnt(8)" ::: "memory");   // tile t resident
        __builtin_amdgcn_s_barrier();
        loadFrags(t % 3, fa, fb);
        asm volatile("s_waitcnt lgkmcnt(0)" ::: "memory"); // reads done
        __builtin_amdgcn_sched_barrier(0);
        __builtin_amdgcn_s_barrier();                      // buffer t%3 free
        if (t < NT - 3) stageTile(t % 3, t + 3);           // t<=20 -> stage t+3
        __builtin_amdgcn_sched_barrier(0);                 // keep issue order
        mfmaTile(fa, fb);
    }
    // ---- tail: tile 22 (buf 1), tile 23 (buf 2) ----
    asm volatile("s_waitcnt vmcnt(4)" ::: "memory");
    __builtin_amdgcn_s_barrier();
    loadFrags(22 % 3, fa, fb);
    asm volatile("s_waitcnt lgkmcnt(0)" ::: "memory");
    __builtin_amdgcn_sched_barrier(0);
    mfmaTile(fa, fb);
    asm volatile("s_waitcnt vmcnt(0)" ::: "memory");
    __builtin_amdgcn_s_barrier();
    loadFrags(23 % 3, fa, fb);
    asm volatile("s_waitcnt lgkmcnt(0)" ::: "memory");
    __builtin_amdgcn_sched_barrier(0);
    mfmaTile(fa, fb);
    __syncthreads();

    // ================= epilogue: two 128-row passes via LDS ==============
    const int part = col0 / 768;                    // block-uniform 0=Q 1=K 2=V
    const int colr0 = col0 - part * 768;
    const int h0 = colr0 >> 6;                      // 4 heads per 256-col tile

#pragma unroll 1
    for (int H = 0; H < 2; ++H) {
        if (wm == H) {
            if (part < 2) {
                // row-major [rl][cl], chunk-XOR swizzle
#pragma unroll
                for (int fj = 0; fj < 4; ++fj) {
                    const int cl = wn * 64 + fj * 16 + arl;
                    const float bias = (part == 0) ? qb[colr0 + cl] : 0.f;
                    const float sc = (part == 0) ? QSCALE : 1.f;
#pragma unroll
                    for (int fi = 0; fi < 8; ++fi) {
#pragma unroll
                        for (int j = 0; j < 4; ++j) {
                            const int rl = fi * 16 + (ahi << 2) + j;
                            smem[rl * 256 + ((((cl >> 3) ^ (rl & 7)) << 3) | (cl & 7))] =
                                f2bf((acc[fi][fj][j] + bias) * sc);
                        }
                    }
                }
            } else {
                // transposed [cl][rl], 4 consecutive rows -> ushort4
#pragma unroll
                for (int fj = 0; fj < 4; ++fj) {
                    const int cl = wn * 64 + fj * 16 + arl;
                    const float bias = vb[colr0 + cl];
#pragma unroll
                    for (int fi = 0; fi < 8; ++fi) {
                        const int rl0 = fi * 16 + (ahi << 2);
                        ushort4 pk;
                        pk.x = f2bf(acc[fi][fj][0] + bias);
                        pk.y = f2bf(acc[fi][fj][1] + bias);
                        pk.z = f2bf(acc[fi][fj][2] + bias);
                        pk.w = f2bf(acc[fi][fj][3] + bias);
                        *(ushort4*)&smem[cl * 128 +
                            ((((rl0 >> 3) ^ (cl & 7)) << 3) | (rl0 & 7))] = pk;
                    }
                }
            }
        }
        __syncthreads();
        const int bbH = (row0 + H * 128) >> 10;
        const int n0H = (row0 + H * 128) & 1023;
        if (part == 0) {
#pragma unroll
            for (int p = 0; p < 8; ++p) {
                const int c = p * 512 + tid;
                const int h = c >> 10, ri = (c >> 3) & 127, j = c & 7;
                bf16x8 v = *(const bf16x8*)&smem[ri * 256 + ((((h << 3) + j) ^ (ri & 7)) << 3)];
                *(bf16x8*)&qw[((size_t)(((bbH * 12 + h0 + h) << 10) + n0H + ri)) * 64 + j * 8] = v;
            }
        } else if (part == 1) {
#pragma unroll
            for (int p = 0; p < 8; ++p) {
                const int c = p * 512 + tid;
                const int h = c >> 10, t2 = (c >> 8) & 3, j = (c >> 5) & 7, r = c & 31;
                const int ri = t2 * 32 + r;
                bf16x8 v = *(const bf16x8*)&smem[ri * 256 + ((((h << 3) + j) ^ (ri & 7)) << 3)];
                *(bf16x8*)&kw[((size_t)(bbH * 12 + h0 + h) << 16) +
                              (((n0H >> 5) + t2) << 11) + (j << 8) + (r << 3)] = v;
            }
        } else {
#pragma unroll
            for (int p = 0; p < 8; ++p) {
                const int c = p * 512 + tid;
                const int h = c >> 10, w = c & 1023;
                const int t2 = w >> 8, f = (w >> 6) & 3, ln = w & 63;
                const int d = ((f >> 1) << 5) + (ln & 31);
                const int rb_ = t2 * 32 + ((f & 1) << 4) + ((ln >> 5) << 3);
                const int ct = h * 64 + d;
                bf16x8 v = *(const bf16x8*)&smem[ct * 128 + (((rb_ >> 3) ^ (ct & 7)) << 3)];
                *(bf16x8*)&vw[((size_t)(bbH * 12 + h0 + h) << 16) +
                              (((n0H >> 5) + t2) << 11) + (f << 9) + (ln << 3)] = v;
            }
        }
        __syncthreads();
    }
}

// ================= proj GEMM (R5 structure, fp32 out + bias) =============
__global__ __launch_bounds__(256) void gemm_proj(
    const u16* __restrict__ A, const u16* __restrict__ B,
    int M, int N, int K, float* __restrict__ outp, const float* __restrict__ bproj)
{
    __shared__ __align__(16) u16 smem[16384];
    u16* lA0 = smem;
    u16* lA1 = smem + 4096;
    u16* lB0 = smem + 8192;
    u16* lB1 = smem + 12288;

    const int tid = threadIdx.x;
    const int lane = tid & 63;
    const int wv = tid >> 6;
    const int nbn = N >> 7;
    const int nwg = gridDim.x;
    const int wg = (blockIdx.x & 7) * (nwg >> 3) + (blockIdx.x >> 3);
    const int bm = wg / nbn, bn = wg % nbn;
    const int row0 = bm << 7, col0 = bn << 7;

    const int c0 = tid, c1 = tid + 256;
    const int ldsOff0 = (wv * 64) * 8;
    const int ldsOff1 = (256 + wv * 64) * 8;

    f32x4 acc[4][4];
#pragma unroll
    for (int i = 0; i < 4; i++)
#pragma unroll
        for (int j = 0; j < 4; j++) acc[i][j] = (f32x4){0.f, 0.f, 0.f, 0.f};

    const int nT = K >> 5;

    auto stage = [&](u16* bufA, u16* bufB, int t) {
        const int k0 = t << 5;
        gload_lds16(&A[(size_t)(row0 + (c0 >> 2)) * K + k0 + (c0 & 3) * 8], bufA + ldsOff0);
        gload_lds16(&A[(size_t)(row0 + (c1 >> 2)) * K + k0 + (c1 & 3) * 8], bufA + ldsOff1);
        gload_lds16(&B[(size_t)(col0 + (c0 >> 2)) * K + k0 + (c0 & 3) * 8], bufB + ldsOff0);
        gload_lds16(&B[(size_t)(col0 + (c1 >> 2)) * K + k0 + (c1 & 3) * 8], bufB + ldsOff1);
    };

    const int wr = (wv >> 1) << 6;
    const int wc = (wv & 1) << 6;

    stage(lA0, lB0, 0);
    __syncthreads();
    for (int t = 0; t < nT; ++t) {
        const u16* As = ((t & 1) ? lA1 : lA0) + (wr + (lane & 15)) * 32 + ((lane >> 4) * 8);
        const u16* Bs = ((t & 1) ? lB1 : lB0) + (wc + (lane & 15)) * 32 + ((lane >> 4) * 8);
        if (t + 1 < nT)
            stage((t & 1) ? lA0 : lA1, (t & 1) ? lB0 : lB1, t + 1);
        bf16x8 af[4], bfr[4];
#pragma unroll
        for (int i = 0; i < 4; i++) af[i] = *(const bf16x8*)(As + i * 16 * 32);
#pragma unroll
        for (int i = 0; i < 4; i++) bfr[i] = *(const bf16x8*)(Bs + i * 16 * 32);
#pragma unroll
        for (int i = 0; i < 4; i++)
#pragma unroll
            for (int j = 0; j < 4; j++)
                acc[i][j] = mfma16(af[i], bfr[j], acc[i][j]);
        __syncthreads();
    }

#pragma unroll
    for (int nj = 0; nj < 4; ++nj) {
        const int col = col0 + wc + nj * 16 + (lane & 15);
        const float bias = bproj[col];
#pragma unroll
        for (int mi = 0; mi < 4; ++mi) {
#pragma unroll
            for (int j = 0; j < 4; ++j) {
                const int row = row0 + wr + mi * 16 + ((lane >> 4) << 2) + j;
                outp[(size_t)row * N + col] = acc[mi][nj][j] + bias;
            }
        }
    }
}

// ---------------- flash attention, swapped-operand 32x32 MFMA ------------
__global__ __launch_bounds__(256, 3) void attn_fwd(
    const u16* __restrict__ Q, const u16* __restrict__ KF,
    const u16* __restrict__ VF, u16* __restrict__ O)
{
    __shared__ __align__(16) u16 tlds[4][32 * 68];
    const int tid = threadIdx.x, lane = tid & 63, wv = tid >> 6;
    const int l31 = lane & 31, hi = lane >> 5;
    const int bh = blockIdx.x % 96;
    const int qbk = blockIdx.x / 96;
    const int q0 = qbk * 128 + wv * 32;
    const size_t base = (size_t)bh << 16;
    const u16* Qp = Q + base;
    const u16* Kp = KF + base;
    const u16* Vp = VF + base;

    bf16x8 qf0, qf1, qf2, qf3;
    {
        const u16* qrow = &Qp[(q0 + l31) * 64 + hi * 8];
        qf0 = *(const bf16x8*)(qrow);
        qf1 = *(const bf16x8*)(qrow + 16);
        qf2 = *(const bf16x8*)(qrow + 32);
        qf3 = *(const bf16x8*)(qrow + 48);
    }

    f32x16 ot0, ot1;
#pragma unroll
    for (int i = 0; i < 16; ++i) { ot0[i] = 0.f; ot1[i] = 0.f; }
    float m = -1e30f, l = 0.f;

    auto loadK = [&](int t2048, bf16x8& f0, bf16x8& f1, bf16x8& f2, bf16x8& f3) {
        const u16* kr = &Kp[t2048 + hi * 256 + l31 * 8];
        f0 = *(const bf16x8*)(kr);
        f1 = *(const bf16x8*)(kr + 512);
        f2 = *(const bf16x8*)(kr + 1024);
        f3 = *(const bf16x8*)(kr + 1536);
    };

    auto body = [&](int t2048, bf16x8 k0, bf16x8 k1, bf16x8 k2, bf16x8 k3) {
        f32x16 s;
#pragma unroll
        for (int i = 0; i < 16; ++i) s[i] = 0.f;
        __builtin_amdgcn_s_setprio(1);
        s = mfma32(k0, qf0, s);
        s = mfma32(k1, qf1, s);
        s = mfma32(k2, qf2, s);
        s = mfma32(k3, qf3, s);
        __builtin_amdgcn_s_setprio(0);
        const u16* vrow = &Vp[t2048 + lane * 8];
        bf16x8 vf00 = *(const bf16x8*)(vrow);
        bf16x8 vf01 = *(const bf16x8*)(vrow + 512);
        bf16x8 vf10 = *(const bf16x8*)(vrow + 1024);
        bf16x8 vf11 = *(const bf16x8*)(vrow + 1536);
        float t0 = fmaxf(fmaxf(s[0], s[1]), fmaxf(s[2], s[3]));
        float t1 = fmaxf(fmaxf(s[4], s[5]), fmaxf(s[6], s[7]));
        float t2 = fmaxf(fmaxf(s[8], s[9]), fmaxf(s[10], s[11]));
        float t3 = fmaxf(fmaxf(s[12], s[13]), fmaxf(s[14], s[15]));
        float tmax = fmaxf(fmaxf(t0, t1), fmaxf(t2, t3));
        tmax = fmaxf(tmax, __shfl_xor(tmax, 32));
        if (!__all(tmax - m <= 8.f)) {
            const float nm = fmaxf(m, tmax);
            const float cr = exp2v(m - nm);
#pragma unroll
            for (int i = 0; i < 16; ++i) { ot0[i] *= cr; ot1[i] *= cr; }
            l *= cr; m = nm;
        }
#pragma unroll
        for (int i = 0; i < 16; ++i) { float p = exp2v(s[i] - m); s[i] = p; l += p; }
        u32 w0 = cvtpk(s[0],  s[1]),  w1 = cvtpk(s[2],  s[3]);
        u32 w2 = cvtpk(s[4],  s[5]),  w3 = cvtpk(s[6],  s[7]);
        u32 w4 = cvtpk(s[8],  s[9]),  w5 = cvtpk(s[10], s[11]);
        u32 w6 = cvtpk(s[12], s[13]), w7 = cvtpk(s[14], s[15]);
        asm("v_permlane32_swap_b32 %0, %1" : "+v"(w0), "+v"(w2));
        asm("v_permlane32_swap_b32 %0, %1" : "+v"(w1), "+v"(w3));
        asm("v_permlane32_swap_b32 %0, %1" : "+v"(w4), "+v"(w6));
        asm("v_permlane32_swap_b32 %0, %1" : "+v"(w5), "+v"(w7));
        union { u32 u[4]; bf16x8 v; } pb0, pb1;
        pb0.u[0] = w0; pb0.u[1] = w1; pb0.u[2] = w2; pb0.u[3] = w3;
        pb1.u[0] = w4; pb1.u[1] = w5; pb1.u[2] = w6; pb1.u[3] = w7;
        __builtin_amdgcn_s_setprio(1);
        ot0 = mfma32(vf00, pb0.v, ot0);
        ot0 = mfma32(vf01, pb1.v, ot0);
        ot1 = mfma32(vf10, pb0.v, ot1);
        ot1 = mfma32(vf11, pb1.v, ot1);
        __builtin_amdgcn_s_setprio(0);
    };

    bf16x8 ka0, ka1, ka2, ka3, kb0, kb1, kb2, kb3;
    loadK(0, ka0, ka1, ka2, ka3);
    for (int kt = 0; kt < 32; kt += 2) {
        loadK((kt + 1) << 11, kb0, kb1, kb2, kb3);
        body(kt << 11, ka0, ka1, ka2, ka3);
        if (kt + 2 < 32) loadK((kt + 2) << 11, ka0, ka1, ka2, ka3);
        body((kt + 1) << 11, kb0, kb1, kb2, kb3);
    }

    const float lt = l + __shfl_xor(l, 32);
    const float inv = 1.f / lt;
    u16* tw = &tlds[wv][0];
    u32* tw32 = (u32*)tw;
#pragma unroll
    for (int i = 0; i < 8; ++i) {
        const int dl = 2 * (i & 1) + 8 * (i >> 1) + 4 * hi;
        tw32[(l31 * 68 + dl) >> 1]      = cvtpk(ot0[2 * i] * inv, ot0[2 * i + 1] * inv);
        tw32[(l31 * 68 + dl + 32) >> 1] = cvtpk(ot1[2 * i] * inv, ot1[2 * i + 1] * inv);
    }
    __syncthreads();
    const int b = bh / 12, h = bh - b * 12;
    const size_t obase = ((size_t)(b << 10) + q0) * 768 + h * 64 + (lane & 7) * 8;
#pragma unroll
    for (int it = 0; it < 4; ++it) {
        const int r = it * 8 + (lane >> 3);
        bf16x8 v = *(const bf16x8*)&tw[r * 68 + (lane & 7) * 8];
        *(bf16x8*)&O[obase + (size_t)r * 768] = v;
    }
}

extern "C" void kernel_launch(void* const* d_in, const int* in_sizes, int n_in,
                              void* d_out, int out_size, void* d_ws, size_t ws_size,
                              hipStream_t stream) {
    const float* x      = (const float*)d_in[0];   // [8,1024,768]
    const float* w_qkv  = (const float*)d_in[1];   // [2304,768]
    const float* q_bias = (const float*)d_in[2];   // [768]
    const float* v_bias = (const float*)d_in[3];   // [768]
    const float* w_proj = (const float*)d_in[4];   // [768,768]
    const float* b_proj = (const float*)d_in[5];   // [768]
    float* out = (float*)d_out;                    // [8,1024,768] fp32

    char* ws = (char*)d_ws;
    u16* xb     = (u16*)(ws);                       // 12,582,912 B
    u16* wqkvb  = (u16*)(ws + 12582912);            //  3,538,944 B
    u16* wprojb = (u16*)(ws + 16121856);            //  1,179,648 B
    u16* qw     = (u16*)(ws + 17301504);            // 12,582,912 B
    u16* kw     = (u16*)(ws + 29884416);            // 12,582,912 B  (K fragment-order)
    u16* vt     = (u16*)(ws + 42467328);            // 12,582,912 B  (V fragment-order)
    u16* ob     = (u16*)(ws + 55050240);            // 12,582,912 B

    cvt_kernel<<<786432 / 256, 256, 0, stream>>>(x, xb, 786432);
    cvt_kernel<<<221184 / 256, 256, 0, stream>>>(w_qkv, wqkvb, 221184);
    cvt_kernel<<< 73728 / 256, 256, 0, stream>>>(w_proj, wprojb, 73728);

    gemm_qkv<<<288, 512, 0, stream>>>(xb, wqkvb, qw, kw, vt, q_bias, v_bias);

    attn_fwd<<<96 * 8, 256, 0, stream>>>(qw, kw, vt, ob);

    gemm_proj<<<(8192 / 128) * (768 / 128), 256, 0, stream>>>(
        ob, wprojb, 8192, 768, 768, out, b_proj);
}

// Round 9
// 114.669 us; speedup vs baseline: 1.4973x; 1.4973x over previous
//
#include <hip/hip_runtime.h>
#include <hip/hip_bf16.h>

typedef unsigned short u16;
typedef unsigned int u32;
typedef __attribute__((ext_vector_type(4))) float f32x4;
typedef __attribute__((ext_vector_type(16))) float f32x16;
typedef __attribute__((ext_vector_type(8))) short bf16x8;

__device__ inline u16 f2bf(float f) {
    union { float f; u32 u; } v; v.f = f;
    u32 r = v.u + 0x7fff + ((v.u >> 16) & 1);
    return (u16)(r >> 16);
}

__device__ inline f32x4 mfma16(bf16x8 a, bf16x8 b, f32x4 c) {
    return __builtin_amdgcn_mfma_f32_16x16x32_bf16(a, b, c, 0, 0, 0);
}
__device__ inline f32x16 mfma32(bf16x8 a, bf16x8 b, f32x16 c) {
    return __builtin_amdgcn_mfma_f32_32x32x16_bf16(a, b, c, 0, 0, 0);
}
__device__ inline u32 cvtpk(float lo, float hi) {
    u32 r;
    asm("v_cvt_pk_bf16_f32 %0, %1, %2" : "=v"(r) : "v"(lo), "v"(hi));
    return r;
}
__device__ inline float exp2v(float x) {
    float r;
    asm("v_exp_f32 %0, %1" : "=v"(r) : "v"(x));
    return r;
}

__device__ inline void gload_lds16(const void* g, const void* l) {
    __builtin_amdgcn_global_load_lds(
        (const __attribute__((address_space(1))) void*)g,
        (__attribute__((address_space(3))) void*)l, 16, 0, 0);
}

// log2(e) * head_dim^-0.5 — folded into q in the QKV epilogue (base-2 softmax)
#define QSCALE 0.18033688f

// ---------------- fp32 -> bf16 conversion, 8 elems/thread ----------------
__global__ void cvt_kernel(const float* __restrict__ in, u16* __restrict__ out, int n8) {
    int i = blockIdx.x * 256 + threadIdx.x;
    if (i >= n8) return;
    const float4* p = (const float4*)in;
    float4 a = p[2 * i], b = p[2 * i + 1];
    bf16x8 v;
    v[0] = (short)f2bf(a.x); v[1] = (short)f2bf(a.y);
    v[2] = (short)f2bf(a.z); v[3] = (short)f2bf(a.w);
    v[4] = (short)f2bf(b.x); v[5] = (short)f2bf(b.y);
    v[6] = (short)f2bf(b.z); v[7] = (short)f2bf(b.w);
    ((bf16x8*)out)[i] = v;
}

// ======= GEMM 128x128 tile, BK=32, 4 waves, 3-buffer counted-vmcnt =======
// C[M,2304 or 768] = A[M,768] * B[N,768]^T. K=768 -> 24 tiles.
// T4 counted vmcnt(8) pipeline (3 LDS buffers, loads never drained to 0 in
// loop), R8 staging/read XOR swizzle (bank-conflict-free), T1 XCD swizzle,
// T5 setprio. Register budget fits 128-VGPR cap: acc 64 + frags 32 + addr.
// EPI 0: Q row-major [bh][n][64]*QSCALE; K,V fragment-order (R4-proven):
//   Kf: (n,d) -> (bh<<16) + (n>>5)*2048 + (d>>3)*256 + (n&31)*8 + (d&7)
//   Vf: (n,d) -> (bh<<16) + (n>>5)*2048 + ((d>>5)*2+((n&31)>>4))*512
//               + (((n>>3)&1)*32 + (d&31))*8 + (n&7)
// EPI 1: fp32 out [M][N] + bias
template <int EPI>
__global__ __launch_bounds__(256) void gemm_bt3(
    const u16* __restrict__ A, const u16* __restrict__ B,
    int nbn,                                  // N/128
    u16* __restrict__ qw, u16* __restrict__ kw, u16* __restrict__ vw,
    const float* __restrict__ qb, const float* __restrict__ vb,
    float* __restrict__ outp, const float* __restrict__ bproj)
{
    // 48 KB: 3 buffers x (A[128][32] | B[128][32]) u16; epilogue reuses 0-1
    __shared__ __align__(16) u16 smem[24576];
    const int K = 768;
    const int NT = 24;
    const int tid = threadIdx.x;
    const int lane = tid & 63, wv = tid >> 6;
    // bijective XCD swizzle (grid % 8 == 0)
    const int nwg = gridDim.x;
    const int wg = (blockIdx.x & 7) * (nwg >> 3) + (blockIdx.x >> 3);
    const int bm = wg / nbn, bn = wg % nbn;
    const int row0 = bm << 7, col0 = bn << 7;

    // ---- staging: 4 gloads/tile; row srow, swizzled source chunk sch ----
    const int srow = tid >> 2;                        // 0..63
    const int sch = (tid & 3) ^ ((srow >> 1) & 3);    // (srow+64 gives same)
    const u16* gA = A + (size_t)(row0 + srow) * K + sch * 8;
    const u16* gB = B + (size_t)(col0 + srow) * K + sch * 8;
    const int ldst = wv * 512;                        // u16, wave-uniform

    auto stageTile = [&](int bufi, int t) {
        u16* base = &smem[bufi * 8192];
        const int k0 = t << 5;
        gload_lds16(gA + k0,                   base + ldst);
        gload_lds16(gA + (size_t)64 * K + k0,  base + 2048 + ldst);
        gload_lds16(gB + k0,                   base + 4096 + ldst);
        gload_lds16(gB + (size_t)64 * K + k0,  base + 4096 + 2048 + ldst);
    };

    // ---- swizzled fragment reads ----
    const int wr = (wv >> 1) << 6;   // wave row offset 0/64
    const int wc = (wv & 1) << 6;    // wave col offset 0/64
    const int arl = lane & 15, ahi = lane >> 4;
    bf16x8 fa[4], fb[4];
    auto loadFrags = [&](int bufi) {
        const u16* bA = &smem[bufi * 8192];
        const u16* bB = &smem[bufi * 8192 + 4096];
#pragma unroll
        for (int fi = 0; fi < 4; ++fi) {
            const int rl = wr + fi * 16 + arl;
            fa[fi] = *(const bf16x8*)(bA + rl * 32 + ((ahi ^ ((rl >> 1) & 3)) << 3));
        }
#pragma unroll
        for (int fj = 0; fj < 4; ++fj) {
            const int cl = wc + fj * 16 + arl;
            fb[fj] = *(const bf16x8*)(bB + cl * 32 + ((ahi ^ ((cl >> 1) & 3)) << 3));
        }
    };

    f32x4 acc[4][4];
#pragma unroll
    for (int i = 0; i < 4; i++)
#pragma unroll
        for (int j = 0; j < 4; j++) acc[i][j] = (f32x4){0.f, 0.f, 0.f, 0.f};

    auto mfmaTile = [&]() {
        __builtin_amdgcn_s_setprio(1);
#pragma unroll
        for (int i = 0; i < 4; i++)
#pragma unroll
            for (int j = 0; j < 4; j++)
                acc[i][j] = mfma16(fa[i], fb[j], acc[i][j]);
        __builtin_amdgcn_s_setprio(0);
    };

    // ---- prologue: 3 tiles staged -> 12 loads in flight ----
    stageTile(0, 0); stageTile(1, 1); stageTile(2, 2);

    // ---- main loop, tiles 0..21: loads stay >= 8-deep across barriers ----
#pragma unroll 1
    for (int t = 0; t < NT - 2; ++t) {
        asm volatile("s_waitcnt vmcnt(8)" ::: "memory");   // tile t resident
        __builtin_amdgcn_s_barrier();
        loadFrags(t % 3);
        asm volatile("s_waitcnt lgkmcnt(0)" ::: "memory");
        __builtin_amdgcn_sched_barrier(0);
        __builtin_amdgcn_s_barrier();                      // buffer t%3 free
        if (t < NT - 3) stageTile(t % 3, t + 3);
        __builtin_amdgcn_sched_barrier(0);
        mfmaTile();
    }
    // ---- tail: tile 22 (buf 1), tile 23 (buf 2) ----
    asm volatile("s_waitcnt vmcnt(4)" ::: "memory");
    __builtin_amdgcn_s_barrier();
    loadFrags(22 % 3);
    asm volatile("s_waitcnt lgkmcnt(0)" ::: "memory");
    __builtin_amdgcn_sched_barrier(0);
    mfmaTile();
    asm volatile("s_waitcnt vmcnt(0)" ::: "memory");
    __builtin_amdgcn_s_barrier();
    loadFrags(23 % 3);
    asm volatile("s_waitcnt lgkmcnt(0)" ::: "memory");
    __builtin_amdgcn_sched_barrier(0);
    mfmaTile();
    __syncthreads();

    if (EPI == 0) {
        // ======= R5-proven epilogue: stage C-tile in smem[0..16383] =======
        const int part = col0 / 768;          // block-uniform: 0=Q 1=K 2=V
        const int colr0 = col0 - part * 768;  // multiple of 128
        const int h0 = colr0 >> 6;            // first of 2 heads in tile
        const int bb = row0 >> 10;            // batch
        const int n0 = row0 & 1023;           // multiple of 128

        if (part < 2) {
#pragma unroll
            for (int nj = 0; nj < 4; ++nj) {
                const int col = wc + nj * 16 + arl;
                const float bias = (part == 0) ? qb[colr0 + col] : 0.f;
                const float sc = (part == 0) ? QSCALE : 1.f;
#pragma unroll
                for (int mi = 0; mi < 4; ++mi) {
#pragma unroll
                    for (int j = 0; j < 4; ++j) {
                        const int row = wr + mi * 16 + (ahi << 2) + j;
                        smem[row * 128 + ((((col >> 3) ^ (row & 7)) << 3) | (col & 7))] =
                            f2bf((acc[mi][nj][j] + bias) * sc);
                    }
                }
            }
        } else {
#pragma unroll
            for (int nj = 0; nj < 4; ++nj) {
                const int col = wc + nj * 16 + arl;
                const float bias = vb[colr0 + col];
#pragma unroll
                for (int mi = 0; mi < 4; ++mi) {
                    const int row = wr + mi * 16 + (ahi << 2);  // row..row+3
                    ushort4 pk;
                    pk.x = f2bf(acc[mi][nj][0] + bias);
                    pk.y = f2bf(acc[mi][nj][1] + bias);
                    pk.z = f2bf(acc[mi][nj][2] + bias);
                    pk.w = f2bf(acc[mi][nj][3] + bias);
                    *(ushort4*)&smem[col * 128 +
                        ((((row >> 3) ^ (col & 7)) << 3) | (row & 7))] = pk;
                }
            }
        }
        __syncthreads();

        if (part == 0) {
#pragma unroll
            for (int p = 0; p < 8; ++p) {
                const int c = p * 256 + tid;
                const int h = c >> 10, ri = (c >> 3) & 127, j = c & 7;
                bf16x8 v = *(const bf16x8*)&smem[ri * 128 + ((((h << 3) + j) ^ (ri & 7)) << 3)];
                *(bf16x8*)&qw[((size_t)(((bb * 12 + h0 + h) << 10) + n0 + ri)) * 64 + j * 8] = v;
            }
        } else if (part == 1) {
#pragma unroll
            for (int p = 0; p < 8; ++p) {
                const int c = p * 256 + tid;
                const int h = c >> 10, t2 = (c >> 8) & 3, j = (c >> 5) & 7, r = c & 31;
                const int ri = t2 * 32 + r;
                bf16x8 v = *(const bf16x8*)&smem[ri * 128 + ((((h << 3) + j) ^ (ri & 7)) << 3)];
                *(bf16x8*)&kw[((size_t)(bb * 12 + h0 + h) << 16) +
                              (((n0 >> 5) + t2) << 11) + (j << 8) + (r << 3)] = v;
            }
        } else {
#pragma unroll
            for (int p = 0; p < 8; ++p) {
                const int c = p * 256 + tid;
                const int h = c >> 10, w = c & 1023;
                const int t2 = w >> 8, f = (w >> 6) & 3, ln = w & 63;
                const int d = ((f >> 1) << 5) + (ln & 31);
                const int rb_ = t2 * 32 + ((f & 1) << 4) + ((ln >> 5) << 3);
                const int ct = h * 64 + d;
                bf16x8 v = *(const bf16x8*)&smem[ct * 128 + (((rb_ >> 3) ^ (ct & 7)) << 3)];
                *(bf16x8*)&vw[((size_t)(bb * 12 + h0 + h) << 16) +
                              (((n0 >> 5) + t2) << 11) + (f << 9) + (ln << 3)] = v;
            }
        }
    } else {
        const int N = nbn << 7;
#pragma unroll
        for (int nj = 0; nj < 4; ++nj) {
            const int col = col0 + wc + nj * 16 + arl;
            const float bias = bproj[col];
#pragma unroll
            for (int mi = 0; mi < 4; ++mi) {
#pragma unroll
                for (int j = 0; j < 4; ++j) {
                    const int row = row0 + wr + mi * 16 + (ahi << 2) + j;
                    outp[(size_t)row * N + col] = acc[mi][nj][j] + bias;
                }
            }
        }
    }
}

// ---------------- flash attention, swapped-operand 32x32 MFMA ------------
__global__ __launch_bounds__(256, 3) void attn_fwd(
    const u16* __restrict__ Q, const u16* __restrict__ KF,
    const u16* __restrict__ VF, u16* __restrict__ O)
{
    __shared__ __align__(16) u16 tlds[4][32 * 68];
    const int tid = threadIdx.x, lane = tid & 63, wv = tid >> 6;
    const int l31 = lane & 31, hi = lane >> 5;
    const int bh = blockIdx.x % 96;
    const int qbk = blockIdx.x / 96;
    const int q0 = qbk * 128 + wv * 32;
    const size_t base = (size_t)bh << 16;
    const u16* Qp = Q + base;
    const u16* Kp = KF + base;
    const u16* Vp = VF + base;

    bf16x8 qf0, qf1, qf2, qf3;
    {
        const u16* qrow = &Qp[(q0 + l31) * 64 + hi * 8];
        qf0 = *(const bf16x8*)(qrow);
        qf1 = *(const bf16x8*)(qrow + 16);
        qf2 = *(const bf16x8*)(qrow + 32);
        qf3 = *(const bf16x8*)(qrow + 48);
    }

    f32x16 ot0, ot1;
#pragma unroll
    for (int i = 0; i < 16; ++i) { ot0[i] = 0.f; ot1[i] = 0.f; }
    float m = -1e30f, l = 0.f;

    auto loadK = [&](int t2048, bf16x8& f0, bf16x8& f1, bf16x8& f2, bf16x8& f3) {
        const u16* kr = &Kp[t2048 + hi * 256 + l31 * 8];
        f0 = *(const bf16x8*)(kr);
        f1 = *(const bf16x8*)(kr + 512);
        f2 = *(const bf16x8*)(kr + 1024);
        f3 = *(const bf16x8*)(kr + 1536);
    };

    auto body = [&](int t2048, bf16x8 k0, bf16x8 k1, bf16x8 k2, bf16x8 k3) {
        f32x16 s;
#pragma unroll
        for (int i = 0; i < 16; ++i) s[i] = 0.f;
        __builtin_amdgcn_s_setprio(1);
        s = mfma32(k0, qf0, s);
        s = mfma32(k1, qf1, s);
        s = mfma32(k2, qf2, s);
        s = mfma32(k3, qf3, s);
        __builtin_amdgcn_s_setprio(0);
        const u16* vrow = &Vp[t2048 + lane * 8];
        bf16x8 vf00 = *(const bf16x8*)(vrow);
        bf16x8 vf01 = *(const bf16x8*)(vrow + 512);
        bf16x8 vf10 = *(const bf16x8*)(vrow + 1024);
        bf16x8 vf11 = *(const bf16x8*)(vrow + 1536);
        float t0 = fmaxf(fmaxf(s[0], s[1]), fmaxf(s[2], s[3]));
        float t1 = fmaxf(fmaxf(s[4], s[5]), fmaxf(s[6], s[7]));
        float t2 = fmaxf(fmaxf(s[8], s[9]), fmaxf(s[10], s[11]));
        float t3 = fmaxf(fmaxf(s[12], s[13]), fmaxf(s[14], s[15]));
        float tmax = fmaxf(fmaxf(t0, t1), fmaxf(t2, t3));
        tmax = fmaxf(tmax, __shfl_xor(tmax, 32));
        if (!__all(tmax - m <= 8.f)) {
            const float nm = fmaxf(m, tmax);
            const float cr = exp2v(m - nm);
#pragma unroll
            for (int i = 0; i < 16; ++i) { ot0[i] *= cr; ot1[i] *= cr; }
            l *= cr; m = nm;
        }
#pragma unroll
        for (int i = 0; i < 16; ++i) { float p = exp2v(s[i] - m); s[i] = p; l += p; }
        u32 w0 = cvtpk(s[0],  s[1]),  w1 = cvtpk(s[2],  s[3]);
        u32 w2 = cvtpk(s[4],  s[5]),  w3 = cvtpk(s[6],  s[7]);
        u32 w4 = cvtpk(s[8],  s[9]),  w5 = cvtpk(s[10], s[11]);
        u32 w6 = cvtpk(s[12], s[13]), w7 = cvtpk(s[14], s[15]);
        asm("v_permlane32_swap_b32 %0, %1" : "+v"(w0), "+v"(w2));
        asm("v_permlane32_swap_b32 %0, %1" : "+v"(w1), "+v"(w3));
        asm("v_permlane32_swap_b32 %0, %1" : "+v"(w4), "+v"(w6));
        asm("v_permlane32_swap_b32 %0, %1" : "+v"(w5), "+v"(w7));
        union { u32 u[4]; bf16x8 v; } pb0, pb1;
        pb0.u[0] = w0; pb0.u[1] = w1; pb0.u[2] = w2; pb0.u[3] = w3;
        pb1.u[0] = w4; pb1.u[1] = w5; pb1.u[2] = w6; pb1.u[3] = w7;
        __builtin_amdgcn_s_setprio(1);
        ot0 = mfma32(vf00, pb0.v, ot0);
        ot0 = mfma32(vf01, pb1.v, ot0);
        ot1 = mfma32(vf10, pb0.v, ot1);
        ot1 = mfma32(vf11, pb1.v, ot1);
        __builtin_amdgcn_s_setprio(0);
    };

    bf16x8 ka0, ka1, ka2, ka3, kb0, kb1, kb2, kb3;
    loadK(0, ka0, ka1, ka2, ka3);
    for (int kt = 0; kt < 32; kt += 2) {
        loadK((kt + 1) << 11, kb0, kb1, kb2, kb3);
        body(kt << 11, ka0, ka1, ka2, ka3);
        if (kt + 2 < 32) loadK((kt + 2) << 11, ka0, ka1, ka2, ka3);
        body((kt + 1) << 11, kb0, kb1, kb2, kb3);
    }

    const float lt = l + __shfl_xor(l, 32);
    const float inv = 1.f / lt;
    u16* tw = &tlds[wv][0];
    u32* tw32 = (u32*)tw;
#pragma unroll
    for (int i = 0; i < 8; ++i) {
        const int dl = 2 * (i & 1) + 8 * (i >> 1) + 4 * hi;
        tw32[(l31 * 68 + dl) >> 1]      = cvtpk(ot0[2 * i] * inv, ot0[2 * i + 1] * inv);
        tw32[(l31 * 68 + dl + 32) >> 1] = cvtpk(ot1[2 * i] * inv, ot1[2 * i + 1] * inv);
    }
    __syncthreads();
    const int b = bh / 12, h = bh - b * 12;
    const size_t obase = ((size_t)(b << 10) + q0) * 768 + h * 64 + (lane & 7) * 8;
#pragma unroll
    for (int it = 0; it < 4; ++it) {
        const int r = it * 8 + (lane >> 3);
        bf16x8 v = *(const bf16x8*)&tw[r * 68 + (lane & 7) * 8];
        *(bf16x8*)&O[obase + (size_t)r * 768] = v;
    }
}

extern "C" void kernel_launch(void* const* d_in, const int* in_sizes, int n_in,
                              void* d_out, int out_size, void* d_ws, size_t ws_size,
                              hipStream_t stream) {
    const float* x      = (const float*)d_in[0];   // [8,1024,768]
    const float* w_qkv  = (const float*)d_in[1];   // [2304,768]
    const float* q_bias = (const float*)d_in[2];   // [768]
    const float* v_bias = (const float*)d_in[3];   // [768]
    const float* w_proj = (const float*)d_in[4];   // [768,768]
    const float* b_proj = (const float*)d_in[5];   // [768]
    float* out = (float*)d_out;                    // [8,1024,768] fp32

    char* ws = (char*)d_ws;
    u16* xb     = (u16*)(ws);                       // 12,582,912 B
    u16* wqkvb  = (u16*)(ws + 12582912);            //  3,538,944 B
    u16* wprojb = (u16*)(ws + 16121856);            //  1,179,648 B
    u16* qw     = (u16*)(ws + 17301504);            // 12,582,912 B
    u16* kw     = (u16*)(ws + 29884416);            // 12,582,912 B  (K fragment-order)
    u16* vt     = (u16*)(ws + 42467328);            // 12,582,912 B  (V fragment-order)
    u16* ob     = (u16*)(ws + 55050240);            // 12,582,912 B

    cvt_kernel<<<786432 / 256, 256, 0, stream>>>(x, xb, 786432);
    cvt_kernel<<<221184 / 256, 256, 0, stream>>>(w_qkv, wqkvb, 221184);
    cvt_kernel<<< 73728 / 256, 256, 0, stream>>>(w_proj, wprojb, 73728);

    gemm_bt3<0><<<(8192 / 128) * (2304 / 128), 256, 0, stream>>>(
        xb, wqkvb, 2304 / 128, qw, kw, vt, q_bias, v_bias, nullptr, nullptr);

    attn_fwd<<<96 * 8, 256, 0, stream>>>(qw, kw, vt, ob);

    gemm_bt3<1><<<(8192 / 128) * (768 / 128), 256, 0, stream>>>(
        ob, wprojb, 768 / 128, nullptr, nullptr, nullptr, nullptr, nullptr, out, b_proj);
}

// Round 10
// 113.422 us; speedup vs baseline: 1.5137x; 1.0110x over previous
//
#include <hip/hip_runtime.h>
#include <hip/hip_bf16.h>

typedef unsigned short u16;
typedef unsigned int u32;
typedef __attribute__((ext_vector_type(4))) float f32x4;
typedef __attribute__((ext_vector_type(16))) float f32x16;
typedef __attribute__((ext_vector_type(8))) short bf16x8;

__device__ inline u16 f2bf(float f) {
    union { float f; u32 u; } v; v.f = f;
    u32 r = v.u + 0x7fff + ((v.u >> 16) & 1);
    return (u16)(r >> 16);
}

__device__ inline f32x4 mfma16(bf16x8 a, bf16x8 b, f32x4 c) {
    return __builtin_amdgcn_mfma_f32_16x16x32_bf16(a, b, c, 0, 0, 0);
}
__device__ inline f32x16 mfma32(bf16x8 a, bf16x8 b, f32x16 c) {
    return __builtin_amdgcn_mfma_f32_32x32x16_bf16(a, b, c, 0, 0, 0);
}
__device__ inline u32 cvtpk(float lo, float hi) {
    u32 r;
    asm("v_cvt_pk_bf16_f32 %0, %1, %2" : "=v"(r) : "v"(lo), "v"(hi));
    return r;
}
__device__ inline float exp2v(float x) {
    float r;
    asm("v_exp_f32 %0, %1" : "=v"(r) : "v"(x));
    return r;
}

__device__ inline void gload_lds16(const void* g, const void* l) {
    __builtin_amdgcn_global_load_lds(
        (const __attribute__((address_space(1))) void*)g,
        (__attribute__((address_space(3))) void*)l, 16, 0, 0);
}

// log2(e) * head_dim^-0.5 — folded into q in the QKV epilogue (base-2 softmax)
#define QSCALE 0.18033688f

// ---------------- fp32 -> bf16 conversion, 8 elems/thread ----------------
__global__ void cvt_kernel(const float* __restrict__ in, u16* __restrict__ out, int n8) {
    int i = blockIdx.x * 256 + threadIdx.x;
    if (i >= n8) return;
    const float4* p = (const float4*)in;
    float4 a = p[2 * i], b = p[2 * i + 1];
    bf16x8 v;
    v[0] = (short)f2bf(a.x); v[1] = (short)f2bf(a.y);
    v[2] = (short)f2bf(a.z); v[3] = (short)f2bf(a.w);
    v[4] = (short)f2bf(b.x); v[5] = (short)f2bf(b.y);
    v[6] = (short)f2bf(b.z); v[7] = (short)f2bf(b.w);
    ((bf16x8*)out)[i] = v;
}

// ======= GEMM 128x128 tile, BK=32, 4 waves, 2-buffer counted-vmcnt =======
// C[M,N] = A[M,768] * B[N,768]^T. K=768 -> 24 tiles.
// Depth-2 pipeline: vmcnt(4) in-loop (never 0 until tail). 32 KB LDS ->
// 5 blocks/CU (20 waves/CU TLP; qkv grid 1152 fits one round, no tail).
// R8 staging/read XOR swizzle, T1 XCD swizzle, T5 setprio.
// EPI 0: Q row-major [bh][n][64]*QSCALE; K,V fragment-order (R4-proven):
//   Kf: (n,d) -> (bh<<16) + (n>>5)*2048 + (d>>3)*256 + (n&31)*8 + (d&7)
//   Vf: (n,d) -> (bh<<16) + (n>>5)*2048 + ((d>>5)*2+((n&31)>>4))*512
//               + (((n>>3)&1)*32 + (d&31))*8 + (n&7)
// EPI 1: fp32 out [M][N] + bias
template <int EPI>
__global__ __launch_bounds__(256) void gemm_bt2(
    const u16* __restrict__ A, const u16* __restrict__ B,
    int nbn,                                  // N/128
    u16* __restrict__ qw, u16* __restrict__ kw, u16* __restrict__ vw,
    const float* __restrict__ qb, const float* __restrict__ vb,
    float* __restrict__ outp, const float* __restrict__ bproj)
{
    // 32 KB: 2 buffers x (A[128][32] | B[128][32]) u16; epilogue reuses all
    __shared__ __align__(16) u16 smem[16384];
    const int K = 768;
    const int NT = 24;
    const int tid = threadIdx.x;
    const int lane = tid & 63, wv = tid >> 6;
    // bijective XCD swizzle (grid % 8 == 0)
    const int nwg = gridDim.x;
    const int wg = (blockIdx.x & 7) * (nwg >> 3) + (blockIdx.x >> 3);
    const int bm = wg / nbn, bn = wg % nbn;
    const int row0 = bm << 7, col0 = bn << 7;

    // ---- staging: 4 gloads/tile; row srow, swizzled source chunk sch ----
    const int srow = tid >> 2;                        // 0..63
    const int sch = (tid & 3) ^ ((srow >> 1) & 3);
    const u16* gA = A + (size_t)(row0 + srow) * K + sch * 8;
    const u16* gB = B + (size_t)(col0 + srow) * K + sch * 8;
    const int ldst = wv * 512;                        // u16, wave-uniform

    auto stageTile = [&](int bufi, int t) {
        u16* base = &smem[bufi * 8192];
        const int k0 = t << 5;
        gload_lds16(gA + k0,                   base + ldst);
        gload_lds16(gA + (size_t)64 * K + k0,  base + 2048 + ldst);
        gload_lds16(gB + k0,                   base + 4096 + ldst);
        gload_lds16(gB + (size_t)64 * K + k0,  base + 4096 + 2048 + ldst);
    };

    // ---- swizzled fragment reads ----
    const int wr = (wv >> 1) << 6;   // wave row offset 0/64
    const int wc = (wv & 1) << 6;    // wave col offset 0/64
    const int arl = lane & 15, ahi = lane >> 4;
    bf16x8 fa[4], fb[4];
    auto loadFrags = [&](int bufi) {
        const u16* bA = &smem[bufi * 8192];
        const u16* bB = &smem[bufi * 8192 + 4096];
#pragma unroll
        for (int fi = 0; fi < 4; ++fi) {
            const int rl = wr + fi * 16 + arl;
            fa[fi] = *(const bf16x8*)(bA + rl * 32 + ((ahi ^ ((rl >> 1) & 3)) << 3));
        }
#pragma unroll
        for (int fj = 0; fj < 4; ++fj) {
            const int cl = wc + fj * 16 + arl;
            fb[fj] = *(const bf16x8*)(bB + cl * 32 + ((ahi ^ ((cl >> 1) & 3)) << 3));
        }
    };

    f32x4 acc[4][4];
#pragma unroll
    for (int i = 0; i < 4; i++)
#pragma unroll
        for (int j = 0; j < 4; j++) acc[i][j] = (f32x4){0.f, 0.f, 0.f, 0.f};

    auto mfmaTile = [&]() {
        __builtin_amdgcn_s_setprio(1);
#pragma unroll
        for (int i = 0; i < 4; i++)
#pragma unroll
            for (int j = 0; j < 4; j++)
                acc[i][j] = mfma16(fa[i], fb[j], acc[i][j]);
        __builtin_amdgcn_s_setprio(0);
    };

    // ---- prologue: 2 tiles staged -> 8 loads in flight ----
    stageTile(0, 0); stageTile(1, 1);

    // ---- main loop, tiles 0..22: loads stay 4-8 deep across barriers ----
#pragma unroll 1
    for (int t = 0; t < NT - 1; ++t) {
        asm volatile("s_waitcnt vmcnt(4)" ::: "memory");   // tile t resident
        __builtin_amdgcn_s_barrier();
        loadFrags(t & 1);
        asm volatile("s_waitcnt lgkmcnt(0)" ::: "memory");
        __builtin_amdgcn_sched_barrier(0);
        __builtin_amdgcn_s_barrier();                      // buffer t&1 free
        if (t < NT - 2) stageTile(t & 1, t + 2);
        __builtin_amdgcn_sched_barrier(0);
        mfmaTile();
    }
    // ---- tail: tile 23 (buf 1) ----
    asm volatile("s_waitcnt vmcnt(0)" ::: "memory");
    __builtin_amdgcn_s_barrier();
    loadFrags((NT - 1) & 1);
    asm volatile("s_waitcnt lgkmcnt(0)" ::: "memory");
    __builtin_amdgcn_sched_barrier(0);
    mfmaTile();
    __syncthreads();

    if (EPI == 0) {
        // ======= R5-proven epilogue: stage C-tile in smem (32 KB) =======
        const int part = col0 / 768;          // block-uniform: 0=Q 1=K 2=V
        const int colr0 = col0 - part * 768;  // multiple of 128
        const int h0 = colr0 >> 6;            // first of 2 heads in tile
        const int bb = row0 >> 10;            // batch
        const int n0 = row0 & 1023;           // multiple of 128

        if (part < 2) {
#pragma unroll
            for (int nj = 0; nj < 4; ++nj) {
                const int col = wc + nj * 16 + arl;
                const float bias = (part == 0) ? qb[colr0 + col] : 0.f;
                const float sc = (part == 0) ? QSCALE : 1.f;
#pragma unroll
                for (int mi = 0; mi < 4; ++mi) {
#pragma unroll
                    for (int j = 0; j < 4; ++j) {
                        const int row = wr + mi * 16 + (ahi << 2) + j;
                        smem[row * 128 + ((((col >> 3) ^ (row & 7)) << 3) | (col & 7))] =
                            f2bf((acc[mi][nj][j] + bias) * sc);
                    }
                }
            }
        } else {
#pragma unroll
            for (int nj = 0; nj < 4; ++nj) {
                const int col = wc + nj * 16 + arl;
                const float bias = vb[colr0 + col];
#pragma unroll
                for (int mi = 0; mi < 4; ++mi) {
                    const int row = wr + mi * 16 + (ahi << 2);  // row..row+3
                    ushort4 pk;
                    pk.x = f2bf(acc[mi][nj][0] + bias);
                    pk.y = f2bf(acc[mi][nj][1] + bias);
                    pk.z = f2bf(acc[mi][nj][2] + bias);
                    pk.w = f2bf(acc[mi][nj][3] + bias);
                    *(ushort4*)&smem[col * 128 +
                        ((((row >> 3) ^ (col & 7)) << 3) | (row & 7))] = pk;
                }
            }
        }
        __syncthreads();

        if (part == 0) {
#pragma unroll
            for (int p = 0; p < 8; ++p) {
                const int c = p * 256 + tid;
                const int h = c >> 10, ri = (c >> 3) & 127, j = c & 7;
                bf16x8 v = *(const bf16x8*)&smem[ri * 128 + ((((h << 3) + j) ^ (ri & 7)) << 3)];
                *(bf16x8*)&qw[((size_t)(((bb * 12 + h0 + h) << 10) + n0 + ri)) * 64 + j * 8] = v;
            }
        } else if (part == 1) {
#pragma unroll
            for (int p = 0; p < 8; ++p) {
                const int c = p * 256 + tid;
                const int h = c >> 10, t2 = (c >> 8) & 3, j = (c >> 5) & 7, r = c & 31;
                const int ri = t2 * 32 + r;
                bf16x8 v = *(const bf16x8*)&smem[ri * 128 + ((((h << 3) + j) ^ (ri & 7)) << 3)];
                *(bf16x8*)&kw[((size_t)(bb * 12 + h0 + h) << 16) +
                              (((n0 >> 5) + t2) << 11) + (j << 8) + (r << 3)] = v;
            }
        } else {
#pragma unroll
            for (int p = 0; p < 8; ++p) {
                const int c = p * 256 + tid;
                const int h = c >> 10, w = c & 1023;
                const int t2 = w >> 8, f = (w >> 6) & 3, ln = w & 63;
                const int d = ((f >> 1) << 5) + (ln & 31);
                const int rb_ = t2 * 32 + ((f & 1) << 4) + ((ln >> 5) << 3);
                const int ct = h * 64 + d;
                bf16x8 v = *(const bf16x8*)&smem[ct * 128 + (((rb_ >> 3) ^ (ct & 7)) << 3)];
                *(bf16x8*)&vw[((size_t)(bb * 12 + h0 + h) << 16) +
                              (((n0 >> 5) + t2) << 11) + (f << 9) + (ln << 3)] = v;
            }
        }
    } else {
        const int N = nbn << 7;
#pragma unroll
        for (int nj = 0; nj < 4; ++nj) {
            const int col = col0 + wc + nj * 16 + arl;
            const float bias = bproj[col];
#pragma unroll
            for (int mi = 0; mi < 4; ++mi) {
#pragma unroll
                for (int j = 0; j < 4; ++j) {
                    const int row = row0 + wr + mi * 16 + (ahi << 2) + j;
                    outp[(size_t)row * N + col] = acc[mi][nj][j] + bias;
                }
            }
        }
    }
}

// ---------------- flash attention, swapped-operand 32x32 MFMA ------------
__global__ __launch_bounds__(256, 3) void attn_fwd(
    const u16* __restrict__ Q, const u16* __restrict__ KF,
    const u16* __restrict__ VF, u16* __restrict__ O)
{
    __shared__ __align__(16) u16 tlds[4][32 * 68];
    const int tid = threadIdx.x, lane = tid & 63, wv = tid >> 6;
    const int l31 = lane & 31, hi = lane >> 5;
    const int bh = blockIdx.x % 96;
    const int qbk = blockIdx.x / 96;
    const int q0 = qbk * 128 + wv * 32;
    const size_t base = (size_t)bh << 16;
    const u16* Qp = Q + base;
    const u16* Kp = KF + base;
    const u16* Vp = VF + base;

    bf16x8 qf0, qf1, qf2, qf3;
    {
        const u16* qrow = &Qp[(q0 + l31) * 64 + hi * 8];
        qf0 = *(const bf16x8*)(qrow);
        qf1 = *(const bf16x8*)(qrow + 16);
        qf2 = *(const bf16x8*)(qrow + 32);
        qf3 = *(const bf16x8*)(qrow + 48);
    }

    f32x16 ot0, ot1;
#pragma unroll
    for (int i = 0; i < 16; ++i) { ot0[i] = 0.f; ot1[i] = 0.f; }
    float m = -1e30f, l = 0.f;

    auto loadK = [&](int t2048, bf16x8& f0, bf16x8& f1, bf16x8& f2, bf16x8& f3) {
        const u16* kr = &Kp[t2048 + hi * 256 + l31 * 8];
        f0 = *(const bf16x8*)(kr);
        f1 = *(const bf16x8*)(kr + 512);
        f2 = *(const bf16x8*)(kr + 1024);
        f3 = *(const bf16x8*)(kr + 1536);
    };

    auto body = [&](int t2048, bf16x8 k0, bf16x8 k1, bf16x8 k2, bf16x8 k3) {
        f32x16 s;
#pragma unroll
        for (int i = 0; i < 16; ++i) s[i] = 0.f;
        __builtin_amdgcn_s_setprio(1);
        s = mfma32(k0, qf0, s);
        s = mfma32(k1, qf1, s);
        s = mfma32(k2, qf2, s);
        s = mfma32(k3, qf3, s);
        __builtin_amdgcn_s_setprio(0);
        const u16* vrow = &Vp[t2048 + lane * 8];
        bf16x8 vf00 = *(const bf16x8*)(vrow);
        bf16x8 vf01 = *(const bf16x8*)(vrow + 512);
        bf16x8 vf10 = *(const bf16x8*)(vrow + 1024);
        bf16x8 vf11 = *(const bf16x8*)(vrow + 1536);
        float t0 = fmaxf(fmaxf(s[0], s[1]), fmaxf(s[2], s[3]));
        float t1 = fmaxf(fmaxf(s[4], s[5]), fmaxf(s[6], s[7]));
        float t2 = fmaxf(fmaxf(s[8], s[9]), fmaxf(s[10], s[11]));
        float t3 = fmaxf(fmaxf(s[12], s[13]), fmaxf(s[14], s[15]));
        float tmax = fmaxf(fmaxf(t0, t1), fmaxf(t2, t3));
        tmax = fmaxf(tmax, __shfl_xor(tmax, 32));
        if (!__all(tmax - m <= 8.f)) {
            const float nm = fmaxf(m, tmax);
            const float cr = exp2v(m - nm);
#pragma unroll
            for (int i = 0; i < 16; ++i) { ot0[i] *= cr; ot1[i] *= cr; }
            l *= cr; m = nm;
        }
#pragma unroll
        for (int i = 0; i < 16; ++i) { float p = exp2v(s[i] - m); s[i] = p; l += p; }
        u32 w0 = cvtpk(s[0],  s[1]),  w1 = cvtpk(s[2],  s[3]);
        u32 w2 = cvtpk(s[4],  s[5]),  w3 = cvtpk(s[6],  s[7]);
        u32 w4 = cvtpk(s[8],  s[9]),  w5 = cvtpk(s[10], s[11]);
        u32 w6 = cvtpk(s[12], s[13]), w7 = cvtpk(s[14], s[15]);
        asm("v_permlane32_swap_b32 %0, %1" : "+v"(w0), "+v"(w2));
        asm("v_permlane32_swap_b32 %0, %1" : "+v"(w1), "+v"(w3));
        asm("v_permlane32_swap_b32 %0, %1" : "+v"(w4), "+v"(w6));
        asm("v_permlane32_swap_b32 %0, %1" : "+v"(w5), "+v"(w7));
        union { u32 u[4]; bf16x8 v; } pb0, pb1;
        pb0.u[0] = w0; pb0.u[1] = w1; pb0.u[2] = w2; pb0.u[3] = w3;
        pb1.u[0] = w4; pb1.u[1] = w5; pb1.u[2] = w6; pb1.u[3] = w7;
        __builtin_amdgcn_s_setprio(1);
        ot0 = mfma32(vf00, pb0.v, ot0);
        ot0 = mfma32(vf01, pb1.v, ot0);
        ot1 = mfma32(vf10, pb0.v, ot1);
        ot1 = mfma32(vf11, pb1.v, ot1);
        __builtin_amdgcn_s_setprio(0);
    };

    bf16x8 ka0, ka1, ka2, ka3, kb0, kb1, kb2, kb3;
    loadK(0, ka0, ka1, ka2, ka3);
    for (int kt = 0; kt < 32; kt += 2) {
        loadK((kt + 1) << 11, kb0, kb1, kb2, kb3);
        body(kt << 11, ka0, ka1, ka2, ka3);
        if (kt + 2 < 32) loadK((kt + 2) << 11, ka0, ka1, ka2, ka3);
        body((kt + 1) << 11, kb0, kb1, kb2, kb3);
    }

    const float lt = l + __shfl_xor(l, 32);
    const float inv = 1.f / lt;
    u16* tw = &tlds[wv][0];
    u32* tw32 = (u32*)tw;
#pragma unroll
    for (int i = 0; i < 8; ++i) {
        const int dl = 2 * (i & 1) + 8 * (i >> 1) + 4 * hi;
        tw32[(l31 * 68 + dl) >> 1]      = cvtpk(ot0[2 * i] * inv, ot0[2 * i + 1] * inv);
        tw32[(l31 * 68 + dl + 32) >> 1] = cvtpk(ot1[2 * i] * inv, ot1[2 * i + 1] * inv);
    }
    __syncthreads();
    const int b = bh / 12, h = bh - b * 12;
    const size_t obase = ((size_t)(b << 10) + q0) * 768 + h * 64 + (lane & 7) * 8;
#pragma unroll
    for (int it = 0; it < 4; ++it) {
        const int r = it * 8 + (lane >> 3);
        bf16x8 v = *(const bf16x8*)&tw[r * 68 + (lane & 7) * 8];
        *(bf16x8*)&O[obase + (size_t)r * 768] = v;
    }
}

extern "C" void kernel_launch(void* const* d_in, const int* in_sizes, int n_in,
                              void* d_out, int out_size, void* d_ws, size_t ws_size,
                              hipStream_t stream) {
    const float* x      = (const float*)d_in[0];   // [8,1024,768]
    const float* w_qkv  = (const float*)d_in[1];   // [2304,768]
    const float* q_bias = (const float*)d_in[2];   // [768]
    const float* v_bias = (const float*)d_in[3];   // [768]
    const float* w_proj = (const float*)d_in[4];   // [768,768]
    const float* b_proj = (const float*)d_in[5];   // [768]
    float* out = (float*)d_out;                    // [8,1024,768] fp32

    char* ws = (char*)d_ws;
    u16* xb     = (u16*)(ws);                       // 12,582,912 B
    u16* wqkvb  = (u16*)(ws + 12582912);            //  3,538,944 B
    u16* wprojb = (u16*)(ws + 16121856);            //  1,179,648 B
    u16* qw     = (u16*)(ws + 17301504);            // 12,582,912 B
    u16* kw     = (u16*)(ws + 29884416);            // 12,582,912 B  (K fragment-order)
    u16* vt     = (u16*)(ws + 42467328);            // 12,582,912 B  (V fragment-order)
    u16* ob     = (u16*)(ws + 55050240);            // 12,582,912 B

    cvt_kernel<<<786432 / 256, 256, 0, stream>>>(x, xb, 786432);
    cvt_kernel<<<221184 / 256, 256, 0, stream>>>(w_qkv, wqkvb, 221184);
    cvt_kernel<<< 73728 / 256, 256, 0, stream>>>(w_proj, wprojb, 73728);

    gemm_bt2<0><<<(8192 / 128) * (2304 / 128), 256, 0, stream>>>(
        xb, wqkvb, 2304 / 128, qw, kw, vt, q_bias, v_bias, nullptr, nullptr);

    attn_fwd<<<96 * 8, 256, 0, stream>>>(qw, kw, vt, ob);

    gemm_bt2<1><<<(8192 / 128) * (768 / 128), 256, 0, stream>>>(
        ob, wprojb, 768 / 128, nullptr, nullptr, nullptr, nullptr, nullptr, out, b_proj);
}